// Round 7
// baseline (991.195 us; speedup 1.0000x reference)
//
#include <hip/hip_runtime.h>
#include <math.h>

#define NN 50000
#define NE 800000
#define NG 512
#define LRELU 0.2f
#define LN_EPS 1e-5f
#define GCAP 128   // max supported in-degree (data Poisson(16), max ~45)

typedef __attribute__((ext_vector_type(8))) short short8;
typedef __attribute__((ext_vector_type(4))) float f32x4;

__device__ inline float b2f(ushort u) { return __uint_as_float((unsigned)u << 16); }
__device__ inline ushort f2b(float v) {
    unsigned ub = __float_as_uint(v);
    return (ushort)((ub + 0x7FFFu + ((ub >> 16) & 1u)) >> 16);
}
__device__ inline void split_bf16(float v, ushort& h, ushort& l) {
    h = f2b(v);
    l = f2b(v - b2f(h));
}

// ---------------------------------------------------------------- CSR build
__global__ void hist_kernel(const int* __restrict__ dst, int* __restrict__ deg) {
    int e = blockIdx.x * blockDim.x + threadIdx.x;
    if (e < NE) atomicAdd(&deg[dst[e]], 1);
}

__global__ __launch_bounds__(1024) void scan1(const int* __restrict__ deg,
                                              int* __restrict__ excl,
                                              int* __restrict__ bsum, int n) {
    __shared__ int s[1024];
    int tid = threadIdx.x;
    int gid = blockIdx.x * 1024 + tid;
    int v = (gid < n) ? deg[gid] : 0;
    s[tid] = v;
    __syncthreads();
    for (int off = 1; off < 1024; off <<= 1) {
        int t = (tid >= off) ? s[tid - off] : 0;
        __syncthreads();
        s[tid] += t;
        __syncthreads();
    }
    if (gid < n) excl[gid] = s[tid] - v;
    if (tid == 1023) bsum[blockIdx.x] = s[1023];
}

__global__ __launch_bounds__(64) void scan2(int* __restrict__ bsum, int nb) {
    int tid = threadIdx.x;
    int orig = (tid < nb) ? bsum[tid] : 0;
    int v = orig;
    #pragma unroll
    for (int off = 1; off < 64; off <<= 1) {
        int t = __shfl_up(v, off, 64);
        if (tid >= off) v += t;
    }
    if (tid < nb) bsum[tid] = v - orig;   // exclusive
}

__global__ __launch_bounds__(1024) void scan3(int* __restrict__ row_ptr,
                                              int* __restrict__ cursor,
                                              const int* __restrict__ bsum, int n) {
    int tid = threadIdx.x;
    int gid = blockIdx.x * 1024 + tid;
    if (gid < n) {
        int v = row_ptr[gid] + bsum[blockIdx.x];
        row_ptr[gid] = v;
        cursor[gid] = v;
    }
    if (gid == 0) row_ptr[n] = NE;
}

__global__ void scatter_kernel(const int* __restrict__ src, const int* __restrict__ dst,
                               int* __restrict__ cursor, int* __restrict__ col_src,
                               const int* __restrict__ batch, int* __restrict__ gcnt) {
    int e = blockIdx.x * blockDim.x + threadIdx.x;
    if (e < NE) {
        int pos = atomicAdd(&cursor[dst[e]], 1);
        col_src[pos] = src[e];
    }
    if (e < NN) atomicAdd(&gcnt[batch[e]], 1);
}

// ---------------------------------------------------------------- weight / input prep
__global__ __launch_bounds__(256) void prep_w(const float* __restrict__ Wl0,
                                              const float* __restrict__ Wr0,
                                              const float* __restrict__ Wl1,
                                              const float* __restrict__ Wr1,
                                              const float* __restrict__ Wl2,
                                              const float* __restrict__ Wr2,
                                              ushort* __restrict__ wt) {
    int id = blockIdx.x * 256 + threadIdx.x;
    const float* Wl; const float* Wr; int K, half, rel; ushort* hi; int losz;
    if (id < 65536) {                    // layer 0: K=128, N=512 (256+256)
        rel = id; K = 128; half = 256; Wl = Wl0; Wr = Wr0;
        hi = wt; losz = 65536;
    } else if (id < 98304) {             // layer 1: K=256, N=128 (64+64)
        rel = id - 65536; K = 256; half = 64; Wl = Wl1; Wr = Wr1;
        hi = wt + 131072; losz = 32768;
    } else if (id < 106496) {            // layer 2: K=64, N=128 (64+64)
        rel = id - 98304; K = 64; half = 64; Wl = Wl2; Wr = Wr2;
        hi = wt + 196608; losz = 8192;
    } else return;
    int n = rel / K, k = rel - n * K;
    float v = (n < half) ? Wl[k * half + n] : Wr[k * half + (n - half)];
    ushort h, l;
    split_bf16(v, h, l);
    hi[rel] = h;
    hi[losz + rel] = l;
}

__global__ __launch_bounds__(256) void split_x(const float* __restrict__ x,
                                               ushort* __restrict__ Xh,
                                               ushort* __restrict__ Xl) {
    int i = blockIdx.x * 256 + threadIdx.x;
    if (i >= NN * 32) return;   // float4 units
    float4 v = ((const float4*)x)[i];
    ushort4 h, l;
    split_bf16(v.x, h.x, l.x);
    split_bf16(v.y, h.y, l.y);
    split_bf16(v.z, h.z, l.z);
    split_bf16(v.w, h.w, l.w);
    ((ushort4*)Xh)[i] = h;
    ((ushort4*)Xl)[i] = l;
}

// ---------------------------------------------------------------- MFMA GEMM (split-bf16)
// C = A @ [Wl|Wr]^T + bias ; 128x128 tile, 4 waves 2x2 of 64x64.
// FUSE=0: A given as bf16 hi/lo planes. FUSE=1: A fp32 + fused LN+relu (stats
// from 64-bucket accumulator) split to bf16 during staging.
// Also writes bf16 copy of cols < bfN to Xb for the gather kernels.
template <int LID, int FUSE>
__global__ __launch_bounds__(256) void gemm_l(const ushort* __restrict__ Ah,
                                              const ushort* __restrict__ Al,
                                              const float* __restrict__ Afp,
                                              const ushort* __restrict__ Bh,
                                              const ushort* __restrict__ Bl,
                                              const float* __restrict__ biasL,
                                              const float* __restrict__ biasR,
                                              int halfN,
                                              float* __restrict__ C,
                                              int M, int Ncol, int K,
                                              ushort* __restrict__ Xb, int bfN,
                                              const float* __restrict__ lnbk,
                                              float invM,
                                              const float* __restrict__ lnG,
                                              const float* __restrict__ lnB) {
    __shared__ ushort sA[2][128][40];
    __shared__ ushort sB[2][128][40];
    __shared__ float sstat[2];
    const int tid = threadIdx.x;
    if (FUSE) {
        if (tid == 0) {
            float s = 0.f, s2 = 0.f;
            for (int i = 0; i < 64; i++) { s += lnbk[i * 4]; s2 += lnbk[i * 4 + 1]; }
            float mu = s * invM;
            float var = s2 * invM - mu * mu;
            sstat[0] = mu;
            sstat[1] = rsqrtf(var + LN_EPS);
        }
        __syncthreads();
    }
    const float mu = FUSE ? sstat[0] : 0.f;
    const float rstd = FUSE ? sstat[1] : 0.f;
    const int w = tid >> 6, lane = tid & 63;
    const int row0 = blockIdx.x * 128;
    const int col0 = blockIdx.y * 128;
    const int wr = (w & 1) * 64, wc = (w >> 1) * 64;
    const int fm = lane & 15;
    const int fk8 = (lane >> 4) * 8;
    f32x4 acc[4][4] = {};

    for (int k0 = 0; k0 < K; k0 += 32) {
        __syncthreads();
        if (FUSE) {
            // A: fp32 + LN + relu + split.  128 rows x 32 k = 1024 float4
            #pragma unroll
            for (int it = 0; it < 4; it++) {
                int idx = it * 256 + tid;
                int r = idx >> 3, q = (idx & 7) * 4;
                int grow = row0 + r, kk = k0 + q;
                float4 v = (grow < M) ? *(const float4*)&Afp[(size_t)grow * K + kk]
                                      : make_float4(0.f, 0.f, 0.f, 0.f);
                float4 gg = *(const float4*)&lnG[kk];
                float4 bb = *(const float4*)&lnB[kk];
                v.x = fmaxf((v.x - mu) * rstd * gg.x + bb.x, 0.f);
                v.y = fmaxf((v.y - mu) * rstd * gg.y + bb.y, 0.f);
                v.z = fmaxf((v.z - mu) * rstd * gg.z + bb.z, 0.f);
                v.w = fmaxf((v.w - mu) * rstd * gg.w + bb.w, 0.f);
                ushort4 hh, ll;
                split_bf16(v.x, hh.x, ll.x);
                split_bf16(v.y, hh.y, ll.y);
                split_bf16(v.z, hh.z, ll.z);
                split_bf16(v.w, hh.w, ll.w);
                *(ushort4*)&sA[0][r][q] = hh;
                *(ushort4*)&sA[1][r][q] = ll;
            }
        } else {
            #pragma unroll
            for (int p = 0; p < 2; p++) {
                const ushort* Ap = p ? Al : Ah;
                #pragma unroll
                for (int it = 0; it < 2; it++) {
                    int idx = it * 256 + tid;
                    int r = idx >> 2, q = (idx & 3) * 8;
                    int grow = row0 + r;
                    short8 va = {};
                    if (grow < M) va = *(const short8*)&Ap[(size_t)grow * K + k0 + q];
                    *(short8*)&sA[p][r][q] = va;
                }
            }
        }
        // B planes
        #pragma unroll
        for (int p = 0; p < 2; p++) {
            const ushort* Bp = p ? Bl : Bh;
            #pragma unroll
            for (int it = 0; it < 2; it++) {
                int idx = it * 256 + tid;
                int r = idx >> 2, q = (idx & 3) * 8;
                *(short8*)&sB[p][r][q] = *(const short8*)&Bp[(size_t)(col0 + r) * K + k0 + q];
            }
        }
        __syncthreads();
        short8 ah[4], al[4];
        #pragma unroll
        for (int m = 0; m < 4; m++) {
            ah[m] = *(const short8*)&sA[0][wr + m * 16 + fm][fk8];
            al[m] = *(const short8*)&sA[1][wr + m * 16 + fm][fk8];
        }
        #pragma unroll
        for (int c = 0; c < 4; c++) {
            short8 bh = *(const short8*)&sB[0][wc + c * 16 + fm][fk8];
            short8 bl = *(const short8*)&sB[1][wc + c * 16 + fm][fk8];
            #pragma unroll
            for (int m = 0; m < 4; m++) {
                acc[m][c] = __builtin_amdgcn_mfma_f32_16x16x32_bf16(ah[m], bh, acc[m][c], 0, 0, 0);
                acc[m][c] = __builtin_amdgcn_mfma_f32_16x16x32_bf16(al[m], bh, acc[m][c], 0, 0, 0);
                acc[m][c] = __builtin_amdgcn_mfma_f32_16x16x32_bf16(ah[m], bl, acc[m][c], 0, 0, 0);
            }
        }
    }
    // epilogue: C/D layout col=lane&15, row=(lane>>4)*4+reg
    const int rbase = (lane >> 4) * 4;
    #pragma unroll
    for (int c = 0; c < 4; c++) {
        int col = col0 + wc + c * 16 + fm;
        float bv = (col < halfN) ? biasL[col] : biasR[col - halfN];
        #pragma unroll
        for (int m = 0; m < 4; m++) {
            #pragma unroll
            for (int r = 0; r < 4; r++) {
                int grow = row0 + wr + m * 16 + rbase + r;
                if (grow < M) {
                    float val = acc[m][c][r] + bv;
                    C[(size_t)grow * Ncol + col] = val;
                    if (col < bfN) Xb[(size_t)grow * bfN + col] = f2b(val);
                }
            }
        }
    }
}

// online-softmax merge of two partials (handles -inf)
__device__ inline void os_merge(float& m, float& l, float4& a,
                                float mb, float lb, const float4& ab) {
    float ms = fmaxf(m, mb);
    float ca = (m == -INFINITY) ? 0.f : __expf(m - ms);
    float cb = (mb == -INFINITY) ? 0.f : __expf(mb - ms);
    l = l * ca + lb * cb;
    a.x = a.x * ca + ab.x * cb;
    a.y = a.y * ca + ab.y * cb;
    a.z = a.z * ca + ab.z * cb;
    a.w = a.w * ca + ab.w * cb;
    m = ms;
}

// ---------------------------------------------------------------- fused GATv2, H=4 (HC=256)
// One block per node; dual-chain unrolled online softmax; bf16 gathers.
__global__ __launch_bounds__(256) void gat4(const ushort* __restrict__ xb,   // [N][256] bf16 xl
                                            const float* __restrict__ xlr,   // [N][512], xr at +256
                                            const float* __restrict__ att,
                                            const float* __restrict__ bias,
                                            const int* __restrict__ row_ptr,
                                            const int* __restrict__ col_src,
                                            float* __restrict__ out,
                                            float* __restrict__ bk) {
    __shared__ float4 sxr[64];
    __shared__ float4 satt[64];
    __shared__ int    scol[GCAP];
    __shared__ float  smw[4][64];
    __shared__ float  slw[4][64];
    __shared__ float4 sacc[4][64];
    const int n = blockIdx.x;
    const int tid = threadIdx.x;
    const int w = tid >> 6, lane = tid & 63;
    const int base = row_ptr[n];
    int deg = row_ptr[n + 1] - base;
    if (deg > GCAP) deg = GCAP;
    if (tid < 64) {
        sxr[tid]  = ((const float4*)(xlr + (size_t)n * 512 + 256))[tid];
        satt[tid] = ((const float4*)att)[tid];
    }
    if (tid < deg) scol[tid] = col_src[base + tid];
    __syncthreads();
    const float4 rxr = sxr[lane], ratt = satt[lane];

    float ma = -INFINITY, la = 0.f, mb = -INFINITY, lb = 0.f;
    float4 aa = {0.f, 0.f, 0.f, 0.f}, ab = {0.f, 0.f, 0.f, 0.f};
    int j = w;
    for (; j + 4 < deg; j += 8) {
        int s0 = scol[j], s1 = scol[j + 4];
        ushort4 u0 = ((const ushort4*)(xb + (size_t)s0 * 256))[lane];
        ushort4 u1 = ((const ushort4*)(xb + (size_t)s1 * 256))[lane];
        float4 x0 = {b2f(u0.x), b2f(u0.y), b2f(u0.z), b2f(u0.w)};
        float4 x1 = {b2f(u1.x), b2f(u1.y), b2f(u1.z), b2f(u1.w)};
        float p0, p1;
        {
            float vx = x0.x + rxr.x; vx = (vx > 0.f) ? vx : LRELU * vx;
            float vy = x0.y + rxr.y; vy = (vy > 0.f) ? vy : LRELU * vy;
            float vz = x0.z + rxr.z; vz = (vz > 0.f) ? vz : LRELU * vz;
            float vw = x0.w + rxr.w; vw = (vw > 0.f) ? vw : LRELU * vw;
            p0 = vx * ratt.x + vy * ratt.y + vz * ratt.z + vw * ratt.w;
        }
        {
            float vx = x1.x + rxr.x; vx = (vx > 0.f) ? vx : LRELU * vx;
            float vy = x1.y + rxr.y; vy = (vy > 0.f) ? vy : LRELU * vy;
            float vz = x1.z + rxr.z; vz = (vz > 0.f) ? vz : LRELU * vz;
            float vw = x1.w + rxr.w; vw = (vw > 0.f) ? vw : LRELU * vw;
            p1 = vx * ratt.x + vy * ratt.y + vz * ratt.z + vw * ratt.w;
        }
        p0 += __shfl_xor(p0, 1, 64);  p1 += __shfl_xor(p1, 1, 64);
        p0 += __shfl_xor(p0, 2, 64);  p1 += __shfl_xor(p1, 2, 64);
        p0 += __shfl_xor(p0, 4, 64);  p1 += __shfl_xor(p1, 4, 64);
        p0 += __shfl_xor(p0, 8, 64);  p1 += __shfl_xor(p1, 8, 64);
        {
            float mn = fmaxf(ma, p0);
            float sc = __expf(ma - mn);
            float ep = __expf(p0 - mn);
            la = la * sc + ep;
            aa.x = fmaf(aa.x, sc, ep * x0.x);
            aa.y = fmaf(aa.y, sc, ep * x0.y);
            aa.z = fmaf(aa.z, sc, ep * x0.z);
            aa.w = fmaf(aa.w, sc, ep * x0.w);
            ma = mn;
        }
        {
            float mn = fmaxf(mb, p1);
            float sc = __expf(mb - mn);
            float ep = __expf(p1 - mn);
            lb = lb * sc + ep;
            ab.x = fmaf(ab.x, sc, ep * x1.x);
            ab.y = fmaf(ab.y, sc, ep * x1.y);
            ab.z = fmaf(ab.z, sc, ep * x1.z);
            ab.w = fmaf(ab.w, sc, ep * x1.w);
            mb = mn;
        }
    }
    if (j < deg) {
        int s0 = scol[j];
        ushort4 u0 = ((const ushort4*)(xb + (size_t)s0 * 256))[lane];
        float4 x0 = {b2f(u0.x), b2f(u0.y), b2f(u0.z), b2f(u0.w)};
        float vx = x0.x + rxr.x; vx = (vx > 0.f) ? vx : LRELU * vx;
        float vy = x0.y + rxr.y; vy = (vy > 0.f) ? vy : LRELU * vy;
        float vz = x0.z + rxr.z; vz = (vz > 0.f) ? vz : LRELU * vz;
        float vw = x0.w + rxr.w; vw = (vw > 0.f) ? vw : LRELU * vw;
        float p0 = vx * ratt.x + vy * ratt.y + vz * ratt.z + vw * ratt.w;
        p0 += __shfl_xor(p0, 1, 64);
        p0 += __shfl_xor(p0, 2, 64);
        p0 += __shfl_xor(p0, 4, 64);
        p0 += __shfl_xor(p0, 8, 64);
        float mn = fmaxf(ma, p0);
        float sc = __expf(ma - mn);
        float ep = __expf(p0 - mn);
        la = la * sc + ep;
        aa.x = fmaf(aa.x, sc, ep * x0.x);
        aa.y = fmaf(aa.y, sc, ep * x0.y);
        aa.z = fmaf(aa.z, sc, ep * x0.z);
        aa.w = fmaf(aa.w, sc, ep * x0.w);
        ma = mn;
    }
    os_merge(ma, la, aa, mb, lb, ab);
    smw[w][lane] = ma;
    slw[w][lane] = la;
    sacc[w][lane] = aa;
    __syncthreads();
    if (w == 0) {
        float m0 = smw[0][lane], m1 = smw[1][lane], m2 = smw[2][lane], m3 = smw[3][lane];
        float ms = fmaxf(fmaxf(m0, m1), fmaxf(m2, m3));
        float c0 = (m0 == -INFINITY) ? 0.f : __expf(m0 - ms);
        float c1 = (m1 == -INFINITY) ? 0.f : __expf(m1 - ms);
        float c2 = (m2 == -INFINITY) ? 0.f : __expf(m2 - ms);
        float c3 = (m3 == -INFINITY) ? 0.f : __expf(m3 - ms);
        float lt = slw[0][lane] * c0 + slw[1][lane] * c1 + slw[2][lane] * c2 + slw[3][lane] * c3;
        float rden = (lt > 0.f) ? 1.f / lt : 0.f;
        float4 a0 = sacc[0][lane], a1 = sacc[1][lane], a2 = sacc[2][lane], a3 = sacc[3][lane];
        float4 bv = ((const float4*)bias)[lane];
        float4 o;
        o.x = (a0.x * c0 + a1.x * c1 + a2.x * c2 + a3.x * c3) * rden + bv.x;
        o.y = (a0.y * c0 + a1.y * c1 + a2.y * c2 + a3.y * c3) * rden + bv.y;
        o.z = (a0.z * c0 + a1.z * c1 + a2.z * c2 + a3.z * c3) * rden + bv.z;
        o.w = (a0.w * c0 + a1.w * c1 + a2.w * c2 + a3.w * c3) * rden + bv.w;
        ((float4*)(out + (size_t)n * 256))[lane] = o;
        float s = o.x + o.y + o.z + o.w;
        float s2 = o.x * o.x + o.y * o.y + o.z * o.z + o.w * o.w;
        #pragma unroll
        for (int off = 32; off > 0; off >>= 1) {
            s  += __shfl_xor(s, off, 64);
            s2 += __shfl_xor(s2, off, 64);
        }
        if (lane == 0) {
            int b = n & 63;
            atomicAdd(&bk[b * 4], s);
            atomicAdd(&bk[b * 4 + 1], s2);
        }
    }
}

// ---------------------------------------------------------------- fused GATv2, H=1 (HC=64)
// 4 nodes per block (one wave each); dual-chain unroll; bf16 gathers.
template <int LID>
__global__ __launch_bounds__(256) void gat1_l(const ushort* __restrict__ xb,   // [N][64] bf16 xl
                                              const float* __restrict__ xlr,   // [N][128], xr at +64
                                              const float* __restrict__ att,
                                              const float* __restrict__ bias,
                                              const int* __restrict__ row_ptr,
                                              const int* __restrict__ col_src,
                                              float* __restrict__ out,
                                              float* __restrict__ bk) {
    __shared__ int    scol[4][GCAP];
    __shared__ float  smw[4][4][16];
    __shared__ float  slw[4][4][16];
    __shared__ float4 sacc[4][4][16];
    const int tid = threadIdx.x;
    const int wv = tid >> 6, lane = tid & 63;
    const int n = blockIdx.x * 4 + wv;   // NN % 4 == 0
    const int base = row_ptr[n];
    int deg = row_ptr[n + 1] - base;
    if (deg > GCAP) deg = GCAP;
    for (int j = lane; j < deg; j += 64) scol[wv][j] = col_src[base + j];
    const int g = lane >> 4, li = lane & 15;
    const float4 rxr  = ((const float4*)(xlr + (size_t)n * 128 + 64))[li];
    const float4 ratt = ((const float4*)att)[li];
    __syncthreads();

    float ma = -INFINITY, la = 0.f, mb = -INFINITY, lb = 0.f;
    float4 aa = {0.f, 0.f, 0.f, 0.f}, ab = {0.f, 0.f, 0.f, 0.f};
    int j = g;
    for (; j + 4 < deg; j += 8) {
        int s0 = scol[wv][j], s1 = scol[wv][j + 4];
        ushort4 u0 = ((const ushort4*)(xb + (size_t)s0 * 64))[li];
        ushort4 u1 = ((const ushort4*)(xb + (size_t)s1 * 64))[li];
        float4 x0 = {b2f(u0.x), b2f(u0.y), b2f(u0.z), b2f(u0.w)};
        float4 x1 = {b2f(u1.x), b2f(u1.y), b2f(u1.z), b2f(u1.w)};
        float p0, p1;
        {
            float vx = x0.x + rxr.x; vx = (vx > 0.f) ? vx : LRELU * vx;
            float vy = x0.y + rxr.y; vy = (vy > 0.f) ? vy : LRELU * vy;
            float vz = x0.z + rxr.z; vz = (vz > 0.f) ? vz : LRELU * vz;
            float vw = x0.w + rxr.w; vw = (vw > 0.f) ? vw : LRELU * vw;
            p0 = vx * ratt.x + vy * ratt.y + vz * ratt.z + vw * ratt.w;
        }
        {
            float vx = x1.x + rxr.x; vx = (vx > 0.f) ? vx : LRELU * vx;
            float vy = x1.y + rxr.y; vy = (vy > 0.f) ? vy : LRELU * vy;
            float vz = x1.z + rxr.z; vz = (vz > 0.f) ? vz : LRELU * vz;
            float vw = x1.w + rxr.w; vw = (vw > 0.f) ? vw : LRELU * vw;
            p1 = vx * ratt.x + vy * ratt.y + vz * ratt.z + vw * ratt.w;
        }
        p0 += __shfl_xor(p0, 1, 64);  p1 += __shfl_xor(p1, 1, 64);
        p0 += __shfl_xor(p0, 2, 64);  p1 += __shfl_xor(p1, 2, 64);
        p0 += __shfl_xor(p0, 4, 64);  p1 += __shfl_xor(p1, 4, 64);
        p0 += __shfl_xor(p0, 8, 64);  p1 += __shfl_xor(p1, 8, 64);
        {
            float mn = fmaxf(ma, p0);
            float sc = __expf(ma - mn);
            float ep = __expf(p0 - mn);
            la = la * sc + ep;
            aa.x = fmaf(aa.x, sc, ep * x0.x);
            aa.y = fmaf(aa.y, sc, ep * x0.y);
            aa.z = fmaf(aa.z, sc, ep * x0.z);
            aa.w = fmaf(aa.w, sc, ep * x0.w);
            ma = mn;
        }
        {
            float mn = fmaxf(mb, p1);
            float sc = __expf(mb - mn);
            float ep = __expf(p1 - mn);
            lb = lb * sc + ep;
            ab.x = fmaf(ab.x, sc, ep * x1.x);
            ab.y = fmaf(ab.y, sc, ep * x1.y);
            ab.z = fmaf(ab.z, sc, ep * x1.z);
            ab.w = fmaf(ab.w, sc, ep * x1.w);
            mb = mn;
        }
    }
    if (j < deg) {
        int s0 = scol[wv][j];
        ushort4 u0 = ((const ushort4*)(xb + (size_t)s0 * 64))[li];
        float4 x0 = {b2f(u0.x), b2f(u0.y), b2f(u0.z), b2f(u0.w)};
        float vx = x0.x + rxr.x; vx = (vx > 0.f) ? vx : LRELU * vx;
        float vy = x0.y + rxr.y; vy = (vy > 0.f) ? vy : LRELU * vy;
        float vz = x0.z + rxr.z; vz = (vz > 0.f) ? vz : LRELU * vz;
        float vw = x0.w + rxr.w; vw = (vw > 0.f) ? vw : LRELU * vw;
        float p0 = vx * ratt.x + vy * ratt.y + vz * ratt.z + vw * ratt.w;
        p0 += __shfl_xor(p0, 1, 64);
        p0 += __shfl_xor(p0, 2, 64);
        p0 += __shfl_xor(p0, 4, 64);
        p0 += __shfl_xor(p0, 8, 64);
        float mn = fmaxf(ma, p0);
        float sc = __expf(ma - mn);
        float ep = __expf(p0 - mn);
        la = la * sc + ep;
        aa.x = fmaf(aa.x, sc, ep * x0.x);
        aa.y = fmaf(aa.y, sc, ep * x0.y);
        aa.z = fmaf(aa.z, sc, ep * x0.z);
        aa.w = fmaf(aa.w, sc, ep * x0.w);
        ma = mn;
    }
    os_merge(ma, la, aa, mb, lb, ab);
    smw[wv][g][li] = ma;
    slw[wv][g][li] = la;
    sacc[wv][g][li] = aa;
    __syncthreads();
    if (g == 0) {
        float m0 = smw[wv][0][li], m1 = smw[wv][1][li], m2 = smw[wv][2][li], m3 = smw[wv][3][li];
        float ms = fmaxf(fmaxf(m0, m1), fmaxf(m2, m3));
        float c0 = (m0 == -INFINITY) ? 0.f : __expf(m0 - ms);
        float c1 = (m1 == -INFINITY) ? 0.f : __expf(m1 - ms);
        float c2 = (m2 == -INFINITY) ? 0.f : __expf(m2 - ms);
        float c3 = (m3 == -INFINITY) ? 0.f : __expf(m3 - ms);
        float lt = slw[wv][0][li] * c0 + slw[wv][1][li] * c1 + slw[wv][2][li] * c2 + slw[wv][3][li] * c3;
        float rden = (lt > 0.f) ? 1.f / lt : 0.f;
        float4 a0 = sacc[wv][0][li], a1 = sacc[wv][1][li], a2 = sacc[wv][2][li], a3 = sacc[wv][3][li];
        float4 bv = ((const float4*)bias)[li];
        float4 o;
        o.x = (a0.x * c0 + a1.x * c1 + a2.x * c2 + a3.x * c3) * rden + bv.x;
        o.y = (a0.y * c0 + a1.y * c1 + a2.y * c2 + a3.y * c3) * rden + bv.y;
        o.z = (a0.z * c0 + a1.z * c1 + a2.z * c2 + a3.z * c3) * rden + bv.z;
        o.w = (a0.w * c0 + a1.w * c1 + a2.w * c2 + a3.w * c3) * rden + bv.w;
        ((float4*)(out + (size_t)n * 64))[li] = o;
        float s = o.x + o.y + o.z + o.w;
        float s2 = o.x * o.x + o.y * o.y + o.z * o.z + o.w * o.w;
        #pragma unroll
        for (int off = 8; off > 0; off >>= 1) {
            s  += __shfl_xor(s, off, 64);
            s2 += __shfl_xor(s2, off, 64);
        }
        if (li == 0) {
            int b = n & 63;
            atomicAdd(&bk[b * 4], s);
            atomicAdd(&bk[b * 4 + 1], s2);
        }
    }
}

// ---------------------------------------------------------------- final LN2 + relu + residual(LN1) + pool
__global__ __launch_bounds__(256) void ln_pool(const float* __restrict__ G,
                                               const float* __restrict__ D,
                                               const float* __restrict__ bk2,
                                               const float* __restrict__ bk1,
                                               float invM,
                                               const float* __restrict__ g2,
                                               const float* __restrict__ b2,
                                               const float* __restrict__ g1,
                                               const float* __restrict__ b1,
                                               const int* __restrict__ batch,
                                               float* __restrict__ Zsum) {
    __shared__ float sm[4];
    if (threadIdx.x == 0) {
        float s = 0.f, s2 = 0.f, t = 0.f, t2 = 0.f;
        for (int i = 0; i < 64; i++) {
            s += bk2[i * 4]; s2 += bk2[i * 4 + 1];
            t += bk1[i * 4]; t2 += bk1[i * 4 + 1];
        }
        float mu2 = s * invM, var2 = s2 * invM - mu2 * mu2;
        float mu1 = t * invM, var1 = t2 * invM - mu1 * mu1;
        sm[0] = mu2; sm[1] = rsqrtf(var2 + LN_EPS);
        sm[2] = mu1; sm[3] = rsqrtf(var1 + LN_EPS);
    }
    __syncthreads();
    int i = blockIdx.x * 256 + threadIdx.x;
    if (i >= NN * 16) return;
    float mu2 = sm[0], rs2 = sm[1], mu1 = sm[2], rs1 = sm[3];
    int n = i >> 4, c4 = (i & 15) * 4;
    float4 v = ((const float4*)G)[i];
    float4 dd = ((const float4*)D)[i];
    float4 gg2 = *(const float4*)&g2[c4];
    float4 bb2 = *(const float4*)&b2[c4];
    float4 gg1 = *(const float4*)&g1[c4];
    float4 bb1 = *(const float4*)&b1[c4];
    v.x = fmaxf((v.x - mu2) * rs2 * gg2.x + bb2.x, 0.f) + fmaxf((dd.x - mu1) * rs1 * gg1.x + bb1.x, 0.f);
    v.y = fmaxf((v.y - mu2) * rs2 * gg2.y + bb2.y, 0.f) + fmaxf((dd.y - mu1) * rs1 * gg1.y + bb1.y, 0.f);
    v.z = fmaxf((v.z - mu2) * rs2 * gg2.z + bb2.z, 0.f) + fmaxf((dd.z - mu1) * rs1 * gg1.z + bb1.z, 0.f);
    v.w = fmaxf((v.w - mu2) * rs2 * gg2.w + bb2.w, 0.f) + fmaxf((dd.w - mu1) * rs1 * gg1.w + bb1.w, 0.f);
    int gr = batch[n];
    atomicAdd(&Zsum[gr * 64 + c4 + 0], v.x);
    atomicAdd(&Zsum[gr * 64 + c4 + 1], v.y);
    atomicAdd(&Zsum[gr * 64 + c4 + 2], v.z);
    atomicAdd(&Zsum[gr * 64 + c4 + 3], v.w);
}

// ---------------------------------------------------------------- MLP head
__global__ __launch_bounds__(64) void mlp_head(const float* __restrict__ Zsum,
                                               const int* __restrict__ gcount,
                                               const float* __restrict__ Wh1,
                                               const float* __restrict__ bh1,
                                               const float* __restrict__ Wh2,
                                               const float* __restrict__ bh2,
                                               float* __restrict__ out) {
    __shared__ float sz[64];
    int g = blockIdx.x, tid = threadIdx.x;
    int cnt = gcount[g];
    float inv = 1.f / (float)(cnt > 1 ? cnt : 1);
    sz[tid] = Zsum[g * 64 + tid] * inv;
    __syncthreads();
    float acc = bh1[tid];
    #pragma unroll
    for (int c = 0; c < 64; c++) acc = fmaf(sz[c], Wh1[c * 64 + tid], acc);
    acc = fmaxf(acc, 0.f);
    float v = acc * Wh2[tid];
    #pragma unroll
    for (int off = 32; off > 0; off >>= 1) v += __shfl_xor(v, off, 64);
    if (tid == 0) out[g] = v + bh2[0];
}

// ---------------------------------------------------------------- launch
extern "C" void kernel_launch(void* const* d_in, const int* in_sizes, int n_in,
                              void* d_out, int out_size, void* d_ws, size_t ws_size,
                              hipStream_t stream) {
    (void)in_sizes; (void)n_in; (void)out_size; (void)ws_size;
    const float* x     = (const float*)d_in[0];
    const int*   ei    = (const int*)d_in[1];
    const int*   batch = (const int*)d_in[2];
    const float* Wl0 = (const float*)d_in[3];  const float* bl0 = (const float*)d_in[4];
    const float* Wr0 = (const float*)d_in[5];  const float* br0 = (const float*)d_in[6];
    const float* at0 = (const float*)d_in[7];  const float* bi0 = (const float*)d_in[8];
    const float* lg0 = (const float*)d_in[9];  const float* lb0 = (const float*)d_in[10];
    const float* Wl1 = (const float*)d_in[11]; const float* bl1 = (const float*)d_in[12];
    const float* Wr1 = (const float*)d_in[13]; const float* br1 = (const float*)d_in[14];
    const float* at1 = (const float*)d_in[15]; const float* bi1 = (const float*)d_in[16];
    const float* lg1 = (const float*)d_in[17]; const float* lb1 = (const float*)d_in[18];
    const float* Wl2 = (const float*)d_in[19]; const float* bl2 = (const float*)d_in[20];
    const float* Wr2 = (const float*)d_in[21]; const float* br2 = (const float*)d_in[22];
    const float* at2 = (const float*)d_in[23]; const float* bi2 = (const float*)d_in[24];
    const float* lg2 = (const float*)d_in[25]; const float* lb2 = (const float*)d_in[26];
    const float* Wh1 = (const float*)d_in[27]; const float* bh1 = (const float*)d_in[28];
    const float* Wh2 = (const float*)d_in[29]; const float* bh2 = (const float*)d_in[30];
    float* out = (float*)d_out;

    const int* srcp = ei;
    const int* dstp = ei + NE;

    char* w = (char*)d_ws;
    size_t off = 0;
    auto carve = [&](size_t bytes) -> void* {
        void* p = w + off;
        off += (bytes + 255) & ~(size_t)255;
        return p;
    };
    float*  AB  = (float*)carve((size_t)NN * 512 * 4);       // gemm fp32 out (xl|xr)
    float*  C   = (float*)carve((size_t)NN * 256 * 4);       // gat4 out; G aliases
    float*  D   = (float*)carve((size_t)NN * 64 * 4);        // gat1<1> out (live to ln_pool)
    ushort* S   = (ushort*)carve((size_t)NN * 256 * 2);      // x hi/lo planes
    ushort* Xb0 = (ushort*)carve((size_t)NN * 256 * 2);      // bf16 xl for gathers
    ushort* wt  = (ushort*)carve(212992 * 2);
    size_t zbytes = 3 * 64 * 4 * 4 + (size_t)NG * 64 * 4 + NG * 4 + (size_t)NN * 4;
    char* zb = (char*)carve(zbytes);
    float* bk0 = (float*)zb;
    float* bk1 = bk0 + 64 * 4;
    float* bk2 = bk1 + 64 * 4;
    float* Zsum = (float*)(zb + 3 * 64 * 4 * 4);
    int*   gcnt = (int*)((char*)Zsum + (size_t)NG * 64 * 4);
    int*   deg  = (int*)((char*)gcnt + NG * 4);
    int* row_ptr = (int*)carve((size_t)(NN + 1) * 4);
    int* cursor  = (int*)carve((size_t)NN * 4);
    int* col_src = (int*)carve((size_t)NE * 4);
    int* bsum    = (int*)carve(64 * 4);

    ushort* Xh = S;                     // [NN][128]
    ushort* Xl = S + (size_t)NN * 128;
    float*  G  = C;                     // [NN][64] layer-2 gat out (C dead after gemm_l<1>)
    ushort* Xb1 = Xb0;                  // [NN][64] (Xb0 dead after gat4)

    const ushort* W0h = wt;            const ushort* W0l = wt + 65536;
    const ushort* W1h = wt + 131072;   const ushort* W1l = wt + 163840;
    const ushort* W2h = wt + 196608;   const ushort* W2l = wt + 204800;

    hipMemsetAsync(zb, 0, zbytes, stream);
    prep_w<<<416, 256, 0, stream>>>(Wl0, Wr0, Wl1, Wr1, Wl2, Wr2, wt);
    split_x<<<(NN * 32 + 255) / 256, 256, 0, stream>>>(x, Xh, Xl);

    // CSR build + graph counts
    hist_kernel<<<(NE + 255) / 256, 256, 0, stream>>>(dstp, deg);
    const int SB = (NN + 1023) / 1024;  // 49
    scan1<<<SB, 1024, 0, stream>>>(deg, row_ptr, bsum, NN);
    scan2<<<1, 64, 0, stream>>>(bsum, SB);
    scan3<<<SB, 1024, 0, stream>>>(row_ptr, cursor, bsum, NN);
    scatter_kernel<<<(NE + 255) / 256, 256, 0, stream>>>(srcp, dstp, cursor, col_src, batch, gcnt);

    const int GR = (NN + 127) / 128;  // 391
    const float invM0 = 1.f / ((float)NN * 256.f);
    const float invM1 = 1.f / ((float)NN * 64.f);

    // ---- layer 0: planes -> xl|xr[512]; GAT(H=4) -> C + bk0
    gemm_l<0, 0><<<dim3(GR, 4), 256, 0, stream>>>(Xh, Xl, nullptr, W0h, W0l, bl0, br0, 256,
                                                  AB, NN, 512, 128, Xb0, 256,
                                                  nullptr, 0.f, nullptr, nullptr);
    gat4<<<NN, 256, 0, stream>>>(Xb0, AB, at0, bi0, row_ptr, col_src, C, bk0);

    // ---- layer 1: LN0+relu fused in staging; C[256] -> xl|xr[128]; GAT -> D + bk1
    gemm_l<1, 1><<<dim3(GR, 1), 256, 0, stream>>>(nullptr, nullptr, C, W1h, W1l, bl1, br1, 64,
                                                  AB, NN, 128, 256, Xb1, 64,
                                                  bk0, invM0, lg0, lb0);
    gat1_l<1><<<NN / 4, 256, 0, stream>>>(Xb1, AB, at1, bi1, row_ptr, col_src, D, bk1);

    // ---- layer 2: LN1+relu fused in staging; D[64] -> xl|xr[128]; GAT -> G + bk2
    gemm_l<2, 1><<<dim3(GR, 1), 256, 0, stream>>>(nullptr, nullptr, D, W2h, W2l, bl2, br2, 64,
                                                  AB, NN, 128, 64, Xb1, 64,
                                                  bk1, invM1, lg1, lb1);
    gat1_l<2><<<NN / 4, 256, 0, stream>>>(Xb1, AB, at2, bi2, row_ptr, col_src, G, bk2);

    // ---- LN2+relu + residual(recomputed LN1+relu) + pool
    ln_pool<<<(NN * 16 + 255) / 256, 256, 0, stream>>>(G, D, bk2, bk1, invM1,
                                                       lg2, lb2, lg1, lb1, batch, Zsum);

    // ---- head
    mlp_head<<<NG, 64, 0, stream>>>(Zsum, gcnt, Wh1, bh1, Wh2, bh2, out);
}

// Round 8
// 923.247 us; speedup vs baseline: 1.0736x; 1.0736x over previous
//
#include <hip/hip_runtime.h>
#include <math.h>

#define NN 50000
#define NE 800000
#define NG 512
#define LRELU 0.2f
#define LN_EPS 1e-5f
#define GCAP 128   // max supported in-degree (data Poisson(16), max ~45)

typedef __attribute__((ext_vector_type(8))) short short8;
typedef __attribute__((ext_vector_type(4))) float f32x4;

__device__ inline float b2f(ushort u) { return __uint_as_float((unsigned)u << 16); }
__device__ inline ushort f2b(float v) {
    unsigned ub = __float_as_uint(v);
    return (ushort)((ub + 0x7FFFu + ((ub >> 16) & 1u)) >> 16);
}
__device__ inline void split_bf16(float v, ushort& h, ushort& l) {
    h = f2b(v);
    l = f2b(v - b2f(h));
}

// ---------------------------------------------------------------- CSR build
__global__ void hist_kernel(const int* __restrict__ dst, int* __restrict__ deg) {
    int e = blockIdx.x * blockDim.x + threadIdx.x;
    if (e < NE) atomicAdd(&deg[dst[e]], 1);
}

__global__ __launch_bounds__(1024) void scan1(const int* __restrict__ deg,
                                              int* __restrict__ excl,
                                              int* __restrict__ bsum, int n) {
    __shared__ int s[1024];
    int tid = threadIdx.x;
    int gid = blockIdx.x * 1024 + tid;
    int v = (gid < n) ? deg[gid] : 0;
    s[tid] = v;
    __syncthreads();
    for (int off = 1; off < 1024; off <<= 1) {
        int t = (tid >= off) ? s[tid - off] : 0;
        __syncthreads();
        s[tid] += t;
        __syncthreads();
    }
    if (gid < n) excl[gid] = s[tid] - v;
    if (tid == 1023) bsum[blockIdx.x] = s[1023];
}

__global__ __launch_bounds__(64) void scan2(int* __restrict__ bsum, int nb) {
    int tid = threadIdx.x;
    int orig = (tid < nb) ? bsum[tid] : 0;
    int v = orig;
    #pragma unroll
    for (int off = 1; off < 64; off <<= 1) {
        int t = __shfl_up(v, off, 64);
        if (tid >= off) v += t;
    }
    if (tid < nb) bsum[tid] = v - orig;   // exclusive
}

__global__ __launch_bounds__(1024) void scan3(int* __restrict__ row_ptr,
                                              int* __restrict__ cursor,
                                              const int* __restrict__ bsum, int n) {
    int tid = threadIdx.x;
    int gid = blockIdx.x * 1024 + tid;
    if (gid < n) {
        int v = row_ptr[gid] + bsum[blockIdx.x];
        row_ptr[gid] = v;
        cursor[gid] = v;
    }
    if (gid == 0) row_ptr[n] = NE;
}

__global__ void scatter_kernel(const int* __restrict__ src, const int* __restrict__ dst,
                               int* __restrict__ cursor, int* __restrict__ col_src,
                               const int* __restrict__ batch, int* __restrict__ gcnt) {
    int e = blockIdx.x * blockDim.x + threadIdx.x;
    if (e < NE) {
        int pos = atomicAdd(&cursor[dst[e]], 1);
        col_src[pos] = src[e];
    }
    if (e < NN) atomicAdd(&gcnt[batch[e]], 1);
}

// ---------------------------------------------------------------- weight / input prep
__global__ __launch_bounds__(256) void prep_w(const float* __restrict__ Wl0,
                                              const float* __restrict__ Wr0,
                                              const float* __restrict__ Wl1,
                                              const float* __restrict__ Wr1,
                                              const float* __restrict__ Wl2,
                                              const float* __restrict__ Wr2,
                                              ushort* __restrict__ wt) {
    int id = blockIdx.x * 256 + threadIdx.x;
    const float* Wl; const float* Wr; int K, half, rel; ushort* hi; int losz;
    if (id < 65536) {                    // layer 0: K=128, N=512 (256+256)
        rel = id; K = 128; half = 256; Wl = Wl0; Wr = Wr0;
        hi = wt; losz = 65536;
    } else if (id < 98304) {             // layer 1: K=256, N=128 (64+64)
        rel = id - 65536; K = 256; half = 64; Wl = Wl1; Wr = Wr1;
        hi = wt + 131072; losz = 32768;
    } else if (id < 106496) {            // layer 2: K=64, N=128 (64+64)
        rel = id - 98304; K = 64; half = 64; Wl = Wl2; Wr = Wr2;
        hi = wt + 196608; losz = 8192;
    } else return;
    int n = rel / K, k = rel - n * K;
    float v = (n < half) ? Wl[k * half + n] : Wr[k * half + (n - half)];
    ushort h, l;
    split_bf16(v, h, l);
    hi[rel] = h;
    hi[losz + rel] = l;
}

__global__ __launch_bounds__(256) void split_x(const float* __restrict__ x,
                                               ushort* __restrict__ Xh,
                                               ushort* __restrict__ Xl) {
    int i = blockIdx.x * 256 + threadIdx.x;
    if (i >= NN * 32) return;   // float4 units
    float4 v = ((const float4*)x)[i];
    ushort4 h, l;
    split_bf16(v.x, h.x, l.x);
    split_bf16(v.y, h.y, l.y);
    split_bf16(v.z, h.z, l.z);
    split_bf16(v.w, h.w, l.w);
    ((ushort4*)Xh)[i] = h;
    ((ushort4*)Xl)[i] = l;
}

// ---------------------------------------------------------------- MFMA GEMM (split-bf16)
template <int LID, int FUSE>
__global__ __launch_bounds__(256) void gemm_l(const ushort* __restrict__ Ah,
                                              const ushort* __restrict__ Al,
                                              const float* __restrict__ Afp,
                                              const ushort* __restrict__ Bh,
                                              const ushort* __restrict__ Bl,
                                              const float* __restrict__ biasL,
                                              const float* __restrict__ biasR,
                                              int halfN,
                                              float* __restrict__ C,
                                              int M, int Ncol, int K,
                                              ushort* __restrict__ Xb, int bfN,
                                              const float* __restrict__ lnbk,
                                              float invM,
                                              const float* __restrict__ lnG,
                                              const float* __restrict__ lnB) {
    __shared__ ushort sA[2][128][40];
    __shared__ ushort sB[2][128][40];
    __shared__ float sstat[2];
    const int tid = threadIdx.x;
    if (FUSE) {
        if (tid == 0) {
            float s = 0.f, s2 = 0.f;
            for (int i = 0; i < 64; i++) { s += lnbk[i * 4]; s2 += lnbk[i * 4 + 1]; }
            float mu = s * invM;
            float var = s2 * invM - mu * mu;
            sstat[0] = mu;
            sstat[1] = rsqrtf(var + LN_EPS);
        }
        __syncthreads();
    }
    const float mu = FUSE ? sstat[0] : 0.f;
    const float rstd = FUSE ? sstat[1] : 0.f;
    const int w = tid >> 6, lane = tid & 63;
    const int row0 = blockIdx.x * 128;
    const int col0 = blockIdx.y * 128;
    const int wr = (w & 1) * 64, wc = (w >> 1) * 64;
    const int fm = lane & 15;
    const int fk8 = (lane >> 4) * 8;
    f32x4 acc[4][4] = {};

    for (int k0 = 0; k0 < K; k0 += 32) {
        __syncthreads();
        if (FUSE) {
            #pragma unroll
            for (int it = 0; it < 4; it++) {
                int idx = it * 256 + tid;
                int r = idx >> 3, q = (idx & 7) * 4;
                int grow = row0 + r, kk = k0 + q;
                float4 v = (grow < M) ? *(const float4*)&Afp[(size_t)grow * K + kk]
                                      : make_float4(0.f, 0.f, 0.f, 0.f);
                float4 gg = *(const float4*)&lnG[kk];
                float4 bb = *(const float4*)&lnB[kk];
                v.x = fmaxf((v.x - mu) * rstd * gg.x + bb.x, 0.f);
                v.y = fmaxf((v.y - mu) * rstd * gg.y + bb.y, 0.f);
                v.z = fmaxf((v.z - mu) * rstd * gg.z + bb.z, 0.f);
                v.w = fmaxf((v.w - mu) * rstd * gg.w + bb.w, 0.f);
                ushort4 hh, ll;
                split_bf16(v.x, hh.x, ll.x);
                split_bf16(v.y, hh.y, ll.y);
                split_bf16(v.z, hh.z, ll.z);
                split_bf16(v.w, hh.w, ll.w);
                *(ushort4*)&sA[0][r][q] = hh;
                *(ushort4*)&sA[1][r][q] = ll;
            }
        } else {
            #pragma unroll
            for (int p = 0; p < 2; p++) {
                const ushort* Ap = p ? Al : Ah;
                #pragma unroll
                for (int it = 0; it < 2; it++) {
                    int idx = it * 256 + tid;
                    int r = idx >> 2, q = (idx & 3) * 8;
                    int grow = row0 + r;
                    short8 va = {};
                    if (grow < M) va = *(const short8*)&Ap[(size_t)grow * K + k0 + q];
                    *(short8*)&sA[p][r][q] = va;
                }
            }
        }
        #pragma unroll
        for (int p = 0; p < 2; p++) {
            const ushort* Bp = p ? Bl : Bh;
            #pragma unroll
            for (int it = 0; it < 2; it++) {
                int idx = it * 256 + tid;
                int r = idx >> 2, q = (idx & 3) * 8;
                *(short8*)&sB[p][r][q] = *(const short8*)&Bp[(size_t)(col0 + r) * K + k0 + q];
            }
        }
        __syncthreads();
        short8 ah[4], al[4];
        #pragma unroll
        for (int m = 0; m < 4; m++) {
            ah[m] = *(const short8*)&sA[0][wr + m * 16 + fm][fk8];
            al[m] = *(const short8*)&sA[1][wr + m * 16 + fm][fk8];
        }
        #pragma unroll
        for (int c = 0; c < 4; c++) {
            short8 bh = *(const short8*)&sB[0][wc + c * 16 + fm][fk8];
            short8 bl = *(const short8*)&sB[1][wc + c * 16 + fm][fk8];
            #pragma unroll
            for (int m = 0; m < 4; m++) {
                acc[m][c] = __builtin_amdgcn_mfma_f32_16x16x32_bf16(ah[m], bh, acc[m][c], 0, 0, 0);
                acc[m][c] = __builtin_amdgcn_mfma_f32_16x16x32_bf16(al[m], bh, acc[m][c], 0, 0, 0);
                acc[m][c] = __builtin_amdgcn_mfma_f32_16x16x32_bf16(ah[m], bl, acc[m][c], 0, 0, 0);
            }
        }
    }
    const int rbase = (lane >> 4) * 4;
    #pragma unroll
    for (int c = 0; c < 4; c++) {
        int col = col0 + wc + c * 16 + fm;
        float bv = (col < halfN) ? biasL[col] : biasR[col - halfN];
        #pragma unroll
        for (int m = 0; m < 4; m++) {
            #pragma unroll
            for (int r = 0; r < 4; r++) {
                int grow = row0 + wr + m * 16 + rbase + r;
                if (grow < M) {
                    float val = acc[m][c][r] + bv;
                    C[(size_t)grow * Ncol + col] = val;
                    if (col < bfN) Xb[(size_t)grow * bfN + col] = f2b(val);
                }
            }
        }
    }
}

// online-softmax merge of two partials (handles -inf)
__device__ inline void os_merge(float& m, float& l, float4& a,
                                float mb, float lb, const float4& ab) {
    float ms = fmaxf(m, mb);
    float ca = (m == -INFINITY) ? 0.f : __expf(m - ms);
    float cb = (mb == -INFINITY) ? 0.f : __expf(mb - ms);
    l = l * ca + lb * cb;
    a.x = a.x * ca + ab.x * cb;
    a.y = a.y * ca + ab.y * cb;
    a.z = a.z * ca + ab.z * cb;
    a.w = a.w * ca + ab.w * cb;
    m = ms;
}

__device__ inline float lrelu_dot(const float4& xv, const float4& rxr, const float4& ratt) {
    float vx = xv.x + rxr.x; vx = (vx > 0.f) ? vx : LRELU * vx;
    float vy = xv.y + rxr.y; vy = (vy > 0.f) ? vy : LRELU * vy;
    float vz = xv.z + rxr.z; vz = (vz > 0.f) ? vz : LRELU * vz;
    float vw = xv.w + rxr.w; vw = (vw > 0.f) ? vw : LRELU * vw;
    return vx * ratt.x + vy * ratt.y + vz * ratt.z + vw * ratt.w;
}

__device__ inline void os_update(float& m, float& l, float4& a, float p, const float4& xv) {
    float mn = fmaxf(m, p);
    float sc = __expf(m - mn);
    float ep = __expf(p - mn);
    l = l * sc + ep;
    a.x = fmaf(a.x, sc, ep * xv.x);
    a.y = fmaf(a.y, sc, ep * xv.y);
    a.z = fmaf(a.z, sc, ep * xv.z);
    a.w = fmaf(a.w, sc, ep * xv.w);
    m = mn;
}

// ---------------------------------------------------------------- fused GATv2, H=4 (HC=256)
// One block (4 waves) per node; quad-chain online softmax; bf16 gathers.
__global__ __launch_bounds__(256) void gat4(const ushort* __restrict__ xb,   // [N][256] bf16 xl
                                            const float* __restrict__ xlr,   // [N][512], xr at +256
                                            const float* __restrict__ att,
                                            const float* __restrict__ bias,
                                            const int* __restrict__ row_ptr,
                                            const int* __restrict__ col_src,
                                            float* __restrict__ out,
                                            float* __restrict__ bk) {
    __shared__ float4 sxr[64];
    __shared__ float4 satt[64];
    __shared__ int    scol[GCAP];
    __shared__ float  smw[4][64];
    __shared__ float  slw[4][64];
    __shared__ float4 sacc[4][64];
    const int n = blockIdx.x;
    const int tid = threadIdx.x;
    const int w = tid >> 6, lane = tid & 63;
    const int base = row_ptr[n];
    int deg = row_ptr[n + 1] - base;
    if (deg > GCAP) deg = GCAP;
    if (tid < 64) {
        sxr[tid]  = ((const float4*)(xlr + (size_t)n * 512 + 256))[tid];
        satt[tid] = ((const float4*)att)[tid];
    }
    if (tid < deg) scol[tid] = col_src[base + tid];
    __syncthreads();
    const float4 rxr = sxr[lane], ratt = satt[lane];

    float m[4] = {-INFINITY, -INFINITY, -INFINITY, -INFINITY};
    float l[4] = {0.f, 0.f, 0.f, 0.f};
    float4 a[4] = {};
    // wave w owns edges j = w + 4c + 16t, c = 0..3 concurrent chains
    for (int t = 0; t < deg; t += 16) {
        int j0 = w + t;
        float4 x0 = {}, x1 = {}, x2 = {}, x3 = {};
        if (j0 < deg)      x0 = [&]{ ushort4 u = ((const ushort4*)(xb + (size_t)scol[j0] * 256))[lane];      return float4{b2f(u.x), b2f(u.y), b2f(u.z), b2f(u.w)}; }();
        if (j0 + 4 < deg)  x1 = [&]{ ushort4 u = ((const ushort4*)(xb + (size_t)scol[j0 + 4] * 256))[lane];  return float4{b2f(u.x), b2f(u.y), b2f(u.z), b2f(u.w)}; }();
        if (j0 + 8 < deg)  x2 = [&]{ ushort4 u = ((const ushort4*)(xb + (size_t)scol[j0 + 8] * 256))[lane];  return float4{b2f(u.x), b2f(u.y), b2f(u.z), b2f(u.w)}; }();
        if (j0 + 12 < deg) x3 = [&]{ ushort4 u = ((const ushort4*)(xb + (size_t)scol[j0 + 12] * 256))[lane]; return float4{b2f(u.x), b2f(u.y), b2f(u.z), b2f(u.w)}; }();
        float p0 = lrelu_dot(x0, rxr, ratt);
        float p1 = lrelu_dot(x1, rxr, ratt);
        float p2 = lrelu_dot(x2, rxr, ratt);
        float p3 = lrelu_dot(x3, rxr, ratt);
        #pragma unroll
        for (int off = 1; off <= 8; off <<= 1) {
            p0 += __shfl_xor(p0, off, 64);
            p1 += __shfl_xor(p1, off, 64);
            p2 += __shfl_xor(p2, off, 64);
            p3 += __shfl_xor(p3, off, 64);
        }
        if (j0 < deg)      os_update(m[0], l[0], a[0], p0, x0);
        if (j0 + 4 < deg)  os_update(m[1], l[1], a[1], p1, x1);
        if (j0 + 8 < deg)  os_update(m[2], l[2], a[2], p2, x2);
        if (j0 + 12 < deg) os_update(m[3], l[3], a[3], p3, x3);
    }
    os_merge(m[0], l[0], a[0], m[1], l[1], a[1]);
    os_merge(m[2], l[2], a[2], m[3], l[3], a[3]);
    os_merge(m[0], l[0], a[0], m[2], l[2], a[2]);
    smw[w][lane] = m[0];
    slw[w][lane] = l[0];
    sacc[w][lane] = a[0];
    __syncthreads();
    if (w == 0) {
        float m0 = smw[0][lane], m1 = smw[1][lane], m2 = smw[2][lane], m3 = smw[3][lane];
        float ms = fmaxf(fmaxf(m0, m1), fmaxf(m2, m3));
        float c0 = (m0 == -INFINITY) ? 0.f : __expf(m0 - ms);
        float c1 = (m1 == -INFINITY) ? 0.f : __expf(m1 - ms);
        float c2 = (m2 == -INFINITY) ? 0.f : __expf(m2 - ms);
        float c3 = (m3 == -INFINITY) ? 0.f : __expf(m3 - ms);
        float lt = slw[0][lane] * c0 + slw[1][lane] * c1 + slw[2][lane] * c2 + slw[3][lane] * c3;
        float rden = (lt > 0.f) ? 1.f / lt : 0.f;
        float4 a0 = sacc[0][lane], a1 = sacc[1][lane], a2 = sacc[2][lane], a3 = sacc[3][lane];
        float4 bv = ((const float4*)bias)[lane];
        float4 o;
        o.x = (a0.x * c0 + a1.x * c1 + a2.x * c2 + a3.x * c3) * rden + bv.x;
        o.y = (a0.y * c0 + a1.y * c1 + a2.y * c2 + a3.y * c3) * rden + bv.y;
        o.z = (a0.z * c0 + a1.z * c1 + a2.z * c2 + a3.z * c3) * rden + bv.z;
        o.w = (a0.w * c0 + a1.w * c1 + a2.w * c2 + a3.w * c3) * rden + bv.w;
        ((float4*)(out + (size_t)n * 256))[lane] = o;
        float s = o.x + o.y + o.z + o.w;
        float s2 = o.x * o.x + o.y * o.y + o.z * o.z + o.w * o.w;
        #pragma unroll
        for (int off = 32; off > 0; off >>= 1) {
            s  += __shfl_xor(s, off, 64);
            s2 += __shfl_xor(s2, off, 64);
        }
        if (lane == 0) {
            int b = n & 63;
            atomicAdd(&bk[b * 4], s);
            atomicAdd(&bk[b * 4 + 1], s2);
        }
    }
}

// ---------------------------------------------------------------- fused GATv2, H=1 (HC=64)
// One wave (64 thr) per node; 4 groups x 4 chains = 16 edges in flight.
template <int LID>
__global__ __launch_bounds__(64) void gat1_l(const ushort* __restrict__ xb,   // [N][64] bf16 xl
                                             const float* __restrict__ xlr,   // [N][128], xr at +64
                                             const float* __restrict__ att,
                                             const float* __restrict__ bias,
                                             const int* __restrict__ row_ptr,
                                             const int* __restrict__ col_src,
                                             float* __restrict__ out,
                                             float* __restrict__ bk) {
    __shared__ int    scol[GCAP];
    __shared__ float  smw[4][16];
    __shared__ float  slw[4][16];
    __shared__ float4 sacc[4][16];
    const int n = blockIdx.x;
    const int lane = threadIdx.x;
    const int base = row_ptr[n];
    int deg = row_ptr[n + 1] - base;
    if (deg > GCAP) deg = GCAP;
    for (int j = lane; j < deg; j += 64) scol[j] = col_src[base + j];
    const int g = lane >> 4, li = lane & 15;
    const float4 rxr  = ((const float4*)(xlr + (size_t)n * 128 + 64))[li];
    const float4 ratt = ((const float4*)att)[li];
    __syncthreads();

    float m[4] = {-INFINITY, -INFINITY, -INFINITY, -INFINITY};
    float l[4] = {0.f, 0.f, 0.f, 0.f};
    float4 a[4] = {};
    // group g owns edges j = g + 4c + 16t, c = 0..3 concurrent chains
    for (int t = 0; t < deg; t += 16) {
        int j0 = g + t;
        float4 x0 = {}, x1 = {}, x2 = {}, x3 = {};
        if (j0 < deg)      { ushort4 u = ((const ushort4*)(xb + (size_t)scol[j0] * 64))[li];      x0 = {b2f(u.x), b2f(u.y), b2f(u.z), b2f(u.w)}; }
        if (j0 + 4 < deg)  { ushort4 u = ((const ushort4*)(xb + (size_t)scol[j0 + 4] * 64))[li];  x1 = {b2f(u.x), b2f(u.y), b2f(u.z), b2f(u.w)}; }
        if (j0 + 8 < deg)  { ushort4 u = ((const ushort4*)(xb + (size_t)scol[j0 + 8] * 64))[li];  x2 = {b2f(u.x), b2f(u.y), b2f(u.z), b2f(u.w)}; }
        if (j0 + 12 < deg) { ushort4 u = ((const ushort4*)(xb + (size_t)scol[j0 + 12] * 64))[li]; x3 = {b2f(u.x), b2f(u.y), b2f(u.z), b2f(u.w)}; }
        float p0 = lrelu_dot(x0, rxr, ratt);
        float p1 = lrelu_dot(x1, rxr, ratt);
        float p2 = lrelu_dot(x2, rxr, ratt);
        float p3 = lrelu_dot(x3, rxr, ratt);
        #pragma unroll
        for (int off = 1; off <= 8; off <<= 1) {
            p0 += __shfl_xor(p0, off, 64);
            p1 += __shfl_xor(p1, off, 64);
            p2 += __shfl_xor(p2, off, 64);
            p3 += __shfl_xor(p3, off, 64);
        }
        if (j0 < deg)      os_update(m[0], l[0], a[0], p0, x0);
        if (j0 + 4 < deg)  os_update(m[1], l[1], a[1], p1, x1);
        if (j0 + 8 < deg)  os_update(m[2], l[2], a[2], p2, x2);
        if (j0 + 12 < deg) os_update(m[3], l[3], a[3], p3, x3);
    }
    os_merge(m[0], l[0], a[0], m[1], l[1], a[1]);
    os_merge(m[2], l[2], a[2], m[3], l[3], a[3]);
    os_merge(m[0], l[0], a[0], m[2], l[2], a[2]);
    smw[g][li] = m[0];
    slw[g][li] = l[0];
    sacc[g][li] = a[0];
    __syncthreads();
    if (g == 0) {
        float m0 = smw[0][li], m1 = smw[1][li], m2 = smw[2][li], m3 = smw[3][li];
        float ms = fmaxf(fmaxf(m0, m1), fmaxf(m2, m3));
        float c0 = (m0 == -INFINITY) ? 0.f : __expf(m0 - ms);
        float c1 = (m1 == -INFINITY) ? 0.f : __expf(m1 - ms);
        float c2 = (m2 == -INFINITY) ? 0.f : __expf(m2 - ms);
        float c3 = (m3 == -INFINITY) ? 0.f : __expf(m3 - ms);
        float lt = slw[0][li] * c0 + slw[1][li] * c1 + slw[2][li] * c2 + slw[3][li] * c3;
        float rden = (lt > 0.f) ? 1.f / lt : 0.f;
        float4 a0 = sacc[0][li], a1 = sacc[1][li], a2 = sacc[2][li], a3 = sacc[3][li];
        float4 bv = ((const float4*)bias)[li];
        float4 o;
        o.x = (a0.x * c0 + a1.x * c1 + a2.x * c2 + a3.x * c3) * rden + bv.x;
        o.y = (a0.y * c0 + a1.y * c1 + a2.y * c2 + a3.y * c3) * rden + bv.y;
        o.z = (a0.z * c0 + a1.z * c1 + a2.z * c2 + a3.z * c3) * rden + bv.z;
        o.w = (a0.w * c0 + a1.w * c1 + a2.w * c2 + a3.w * c3) * rden + bv.w;
        ((float4*)(out + (size_t)n * 64))[li] = o;
        float s = o.x + o.y + o.z + o.w;
        float s2 = o.x * o.x + o.y * o.y + o.z * o.z + o.w * o.w;
        #pragma unroll
        for (int off = 8; off > 0; off >>= 1) {
            s  += __shfl_xor(s, off, 64);
            s2 += __shfl_xor(s2, off, 64);
        }
        if (li == 0) {
            int b = n & 63;
            atomicAdd(&bk[b * 4], s);
            atomicAdd(&bk[b * 4 + 1], s2);
        }
    }
}

// ---------------------------------------------------------------- final LN2 + relu + residual(LN1) + pool
__global__ __launch_bounds__(256) void ln_pool(const float* __restrict__ G,
                                               const float* __restrict__ D,
                                               const float* __restrict__ bk2,
                                               const float* __restrict__ bk1,
                                               float invM,
                                               const float* __restrict__ g2,
                                               const float* __restrict__ b2,
                                               const float* __restrict__ g1,
                                               const float* __restrict__ b1,
                                               const int* __restrict__ batch,
                                               float* __restrict__ Zsum) {
    __shared__ float sm[4];
    if (threadIdx.x == 0) {
        float s = 0.f, s2 = 0.f, t = 0.f, t2 = 0.f;
        for (int i = 0; i < 64; i++) {
            s += bk2[i * 4]; s2 += bk2[i * 4 + 1];
            t += bk1[i * 4]; t2 += bk1[i * 4 + 1];
        }
        float mu2 = s * invM, var2 = s2 * invM - mu2 * mu2;
        float mu1 = t * invM, var1 = t2 * invM - mu1 * mu1;
        sm[0] = mu2; sm[1] = rsqrtf(var2 + LN_EPS);
        sm[2] = mu1; sm[3] = rsqrtf(var1 + LN_EPS);
    }
    __syncthreads();
    int i = blockIdx.x * 256 + threadIdx.x;
    if (i >= NN * 16) return;
    float mu2 = sm[0], rs2 = sm[1], mu1 = sm[2], rs1 = sm[3];
    int n = i >> 4, c4 = (i & 15) * 4;
    float4 v = ((const float4*)G)[i];
    float4 dd = ((const float4*)D)[i];
    float4 gg2 = *(const float4*)&g2[c4];
    float4 bb2 = *(const float4*)&b2[c4];
    float4 gg1 = *(const float4*)&g1[c4];
    float4 bb1 = *(const float4*)&b1[c4];
    v.x = fmaxf((v.x - mu2) * rs2 * gg2.x + bb2.x, 0.f) + fmaxf((dd.x - mu1) * rs1 * gg1.x + bb1.x, 0.f);
    v.y = fmaxf((v.y - mu2) * rs2 * gg2.y + bb2.y, 0.f) + fmaxf((dd.y - mu1) * rs1 * gg1.y + bb1.y, 0.f);
    v.z = fmaxf((v.z - mu2) * rs2 * gg2.z + bb2.z, 0.f) + fmaxf((dd.z - mu1) * rs1 * gg1.z + bb1.z, 0.f);
    v.w = fmaxf((v.w - mu2) * rs2 * gg2.w + bb2.w, 0.f) + fmaxf((dd.w - mu1) * rs1 * gg1.w + bb1.w, 0.f);
    int gr = batch[n];
    atomicAdd(&Zsum[gr * 64 + c4 + 0], v.x);
    atomicAdd(&Zsum[gr * 64 + c4 + 1], v.y);
    atomicAdd(&Zsum[gr * 64 + c4 + 2], v.z);
    atomicAdd(&Zsum[gr * 64 + c4 + 3], v.w);
}

// ---------------------------------------------------------------- MLP head
__global__ __launch_bounds__(64) void mlp_head(const float* __restrict__ Zsum,
                                               const int* __restrict__ gcount,
                                               const float* __restrict__ Wh1,
                                               const float* __restrict__ bh1,
                                               const float* __restrict__ Wh2,
                                               const float* __restrict__ bh2,
                                               float* __restrict__ out) {
    __shared__ float sz[64];
    int g = blockIdx.x, tid = threadIdx.x;
    int cnt = gcount[g];
    float inv = 1.f / (float)(cnt > 1 ? cnt : 1);
    sz[tid] = Zsum[g * 64 + tid] * inv;
    __syncthreads();
    float acc = bh1[tid];
    #pragma unroll
    for (int c = 0; c < 64; c++) acc = fmaf(sz[c], Wh1[c * 64 + tid], acc);
    acc = fmaxf(acc, 0.f);
    float v = acc * Wh2[tid];
    #pragma unroll
    for (int off = 32; off > 0; off >>= 1) v += __shfl_xor(v, off, 64);
    if (tid == 0) out[g] = v + bh2[0];
}

// ---------------------------------------------------------------- launch
extern "C" void kernel_launch(void* const* d_in, const int* in_sizes, int n_in,
                              void* d_out, int out_size, void* d_ws, size_t ws_size,
                              hipStream_t stream) {
    (void)in_sizes; (void)n_in; (void)out_size; (void)ws_size;
    const float* x     = (const float*)d_in[0];
    const int*   ei    = (const int*)d_in[1];
    const int*   batch = (const int*)d_in[2];
    const float* Wl0 = (const float*)d_in[3];  const float* bl0 = (const float*)d_in[4];
    const float* Wr0 = (const float*)d_in[5];  const float* br0 = (const float*)d_in[6];
    const float* at0 = (const float*)d_in[7];  const float* bi0 = (const float*)d_in[8];
    const float* lg0 = (const float*)d_in[9];  const float* lb0 = (const float*)d_in[10];
    const float* Wl1 = (const float*)d_in[11]; const float* bl1 = (const float*)d_in[12];
    const float* Wr1 = (const float*)d_in[13]; const float* br1 = (const float*)d_in[14];
    const float* at1 = (const float*)d_in[15]; const float* bi1 = (const float*)d_in[16];
    const float* lg1 = (const float*)d_in[17]; const float* lb1 = (const float*)d_in[18];
    const float* Wl2 = (const float*)d_in[19]; const float* bl2 = (const float*)d_in[20];
    const float* Wr2 = (const float*)d_in[21]; const float* br2 = (const float*)d_in[22];
    const float* at2 = (const float*)d_in[23]; const float* bi2 = (const float*)d_in[24];
    const float* lg2 = (const float*)d_in[25]; const float* lb2 = (const float*)d_in[26];
    const float* Wh1 = (const float*)d_in[27]; const float* bh1 = (const float*)d_in[28];
    const float* Wh2 = (const float*)d_in[29]; const float* bh2 = (const float*)d_in[30];
    float* out = (float*)d_out;

    const int* srcp = ei;
    const int* dstp = ei + NE;

    char* w = (char*)d_ws;
    size_t off = 0;
    auto carve = [&](size_t bytes) -> void* {
        void* p = w + off;
        off += (bytes + 255) & ~(size_t)255;
        return p;
    };
    float*  AB  = (float*)carve((size_t)NN * 512 * 4);       // gemm fp32 out (xl|xr)
    float*  C   = (float*)carve((size_t)NN * 256 * 4);       // gat4 out; G aliases
    float*  D   = (float*)carve((size_t)NN * 64 * 4);        // gat1<1> out (live to ln_pool)
    ushort* S   = (ushort*)carve((size_t)NN * 256 * 2);      // x hi/lo planes
    ushort* Xb0 = (ushort*)carve((size_t)NN * 256 * 2);      // bf16 xl for gathers
    ushort* wt  = (ushort*)carve(212992 * 2);
    size_t zbytes = 3 * 64 * 4 * 4 + (size_t)NG * 64 * 4 + NG * 4 + (size_t)NN * 4;
    char* zb = (char*)carve(zbytes);
    float* bk0 = (float*)zb;
    float* bk1 = bk0 + 64 * 4;
    float* bk2 = bk1 + 64 * 4;
    float* Zsum = (float*)(zb + 3 * 64 * 4 * 4);
    int*   gcnt = (int*)((char*)Zsum + (size_t)NG * 64 * 4);
    int*   deg  = (int*)((char*)gcnt + NG * 4);
    int* row_ptr = (int*)carve((size_t)(NN + 1) * 4);
    int* cursor  = (int*)carve((size_t)NN * 4);
    int* col_src = (int*)carve((size_t)NE * 4);
    int* bsum    = (int*)carve(64 * 4);

    ushort* Xh = S;                     // [NN][128]
    ushort* Xl = S + (size_t)NN * 128;
    float*  G  = C;                     // [NN][64] layer-2 gat out (C dead after gemm_l<1>)
    ushort* Xb1 = Xb0;                  // [NN][64] (Xb0 dead after gat4)

    const ushort* W0h = wt;            const ushort* W0l = wt + 65536;
    const ushort* W1h = wt + 131072;   const ushort* W1l = wt + 163840;
    const ushort* W2h = wt + 196608;   const ushort* W2l = wt + 204800;

    hipMemsetAsync(zb, 0, zbytes, stream);
    prep_w<<<416, 256, 0, stream>>>(Wl0, Wr0, Wl1, Wr1, Wl2, Wr2, wt);
    split_x<<<(NN * 32 + 255) / 256, 256, 0, stream>>>(x, Xh, Xl);

    // CSR build + graph counts
    hist_kernel<<<(NE + 255) / 256, 256, 0, stream>>>(dstp, deg);
    const int SB = (NN + 1023) / 1024;  // 49
    scan1<<<SB, 1024, 0, stream>>>(deg, row_ptr, bsum, NN);
    scan2<<<1, 64, 0, stream>>>(bsum, SB);
    scan3<<<SB, 1024, 0, stream>>>(row_ptr, cursor, bsum, NN);
    scatter_kernel<<<(NE + 255) / 256, 256, 0, stream>>>(srcp, dstp, cursor, col_src, batch, gcnt);

    const int GR = (NN + 127) / 128;  // 391
    const float invM0 = 1.f / ((float)NN * 256.f);
    const float invM1 = 1.f / ((float)NN * 64.f);

    // ---- layer 0: planes -> xl|xr[512]; GAT(H=4) -> C + bk0
    gemm_l<0, 0><<<dim3(GR, 4), 256, 0, stream>>>(Xh, Xl, nullptr, W0h, W0l, bl0, br0, 256,
                                                  AB, NN, 512, 128, Xb0, 256,
                                                  nullptr, 0.f, nullptr, nullptr);
    gat4<<<NN, 256, 0, stream>>>(Xb0, AB, at0, bi0, row_ptr, col_src, C, bk0);

    // ---- layer 1: LN0+relu fused in staging; C[256] -> xl|xr[128]; GAT -> D + bk1
    gemm_l<1, 1><<<dim3(GR, 1), 256, 0, stream>>>(nullptr, nullptr, C, W1h, W1l, bl1, br1, 64,
                                                  AB, NN, 128, 256, Xb1, 64,
                                                  bk0, invM0, lg0, lb0);
    gat1_l<1><<<NN, 64, 0, stream>>>(Xb1, AB, at1, bi1, row_ptr, col_src, D, bk1);

    // ---- layer 2: LN1+relu fused in staging; D[64] -> xl|xr[128]; GAT -> G + bk2
    gemm_l<2, 1><<<dim3(GR, 1), 256, 0, stream>>>(nullptr, nullptr, D, W2h, W2l, bl2, br2, 64,
                                                  AB, NN, 128, 64, Xb1, 64,
                                                  bk1, invM1, lg1, lb1);
    gat1_l<2><<<NN, 64, 0, stream>>>(Xb1, AB, at2, bi2, row_ptr, col_src, G, bk2);

    // ---- LN2+relu + residual(recomputed LN1+relu) + pool
    ln_pool<<<(NN * 16 + 255) / 256, 256, 0, stream>>>(G, D, bk2, bk1, invM1,
                                                       lg2, lb2, lg1, lb1, batch, Zsum);

    // ---- head
    mlp_head<<<NG, 64, 0, stream>>>(Zsum, gcnt, Wh1, bh1, Wh2, bh2, out);
}